// Round 1
// baseline (146.564 us; speedup 1.0000x reference)
//
#include <hip/hip_runtime.h>
#include <hip/hip_bf16.h>

#define B_TOTAL 16384
#define EMB 128
#define NBLK 512
#define TPB 512                 // 8 waves
#define ROWS_PER_WAVE 4         // 16384 / (512 blocks * 8 waves)
#define KG_LAMBDA 1e-5f

// RNE float->bf16, packed pair (a in low 16, b in high 16)
__device__ __forceinline__ unsigned pack_bf16x2(float a, float b) {
  unsigned ua = __float_as_uint(a);
  unsigned ub = __float_as_uint(b);
  ua = (ua + 0x7fffu + ((ua >> 16) & 1u)) >> 16;
  ub = (ub + 0x7fffu + ((ub >> 16) & 1u)) >> 16;
  return ua | (ub << 16);
}

__global__ __launch_bounds__(TPB, 4) void sur_main(
    const int* __restrict__ h, const int* __restrict__ r,
    const int* __restrict__ pos_t, const int* __restrict__ neg_t,
    const float* __restrict__ ent, const float* __restrict__ rel,
    const float* __restrict__ htw1, const float* __restrict__ htw2,
    const float* __restrict__ hbias,
    const float* __restrict__ rtw1, const float* __restrict__ rtw2,
    const float* __restrict__ rbias,
    const float* __restrict__ W, float* __restrict__ partials) {
  // W packed as bf16 pairs: wp[i*64 + j2] holds W[i][2*j2], W[i][2*j2+1]
  __shared__ unsigned wp[256 * 64];      // 64 KB
  __shared__ float crossbuf[8][256];     // 8 KB, one row per wave
  __shared__ float redbuf[2][8];

  const int tid = threadIdx.x;
  const int lane = tid & 63;
  const int wave = tid >> 6;
  const int c0 = lane * 2;               // this lane's two columns

  // stage sem_trans_w -> LDS as packed bf16 (coalesced float2 reads)
  for (int k = tid; k < 256 * 64; k += TPB) {
    float2 w2 = *reinterpret_cast<const float2*>(W + 2 * k);
    wp[k] = pack_bf16x2(w2.x, w2.y);
  }

  // per-lane slices of the small transform vectors (loaded once)
  const float htw1v0 = htw1[c0], htw1v1 = htw1[c0 + 1];
  const float htw2v0 = htw2[c0], htw2v1 = htw2[c0 + 1];
  const float hb0 = hbias[c0],   hb1 = hbias[c0 + 1];
  const float rtw1v0 = rtw1[c0], rtw1v1 = rtw1[c0 + 1];
  const float rtw2v0 = rtw2[c0], rtw2v1 = rtw2[c0 + 1];
  const float rb0 = rbias[c0],   rb1 = rbias[c0 + 1];

  __syncthreads();

  float acc_kg = 0.f, acc_l2 = 0.f;
  const int row_base = blockIdx.x * (ROWS_PER_WAVE * (TPB / 64)) + wave * ROWS_PER_WAVE;

  for (int rr = 0; rr < ROWS_PER_WAVE; ++rr) {
    const int row = row_base + rr;
    const int hi = h[row], ri = r[row], pi = pos_t[row], ni = neg_t[row];

    const float2 he = *reinterpret_cast<const float2*>(ent + hi * EMB + c0);
    const float2 re = *reinterpret_cast<const float2*>(rel + ri * EMB + c0);
    const float2 pe = *reinterpret_cast<const float2*>(ent + pi * EMB + c0);
    const float2 ne = *reinterpret_cast<const float2*>(ent + ni * EMB + c0);

    // four row-dots, reduced across the wave together
    float p_rw1 = re.x * htw1v0 + re.y * htw1v1;   // r_e @ h_trans_w1
    float p_rw2 = re.x * htw2v0 + re.y * htw2v1;   // r_e @ h_trans_w2
    float p_hw1 = he.x * rtw1v0 + he.y * rtw1v1;   // h_e @ r_trans_w1
    float p_hw2 = he.x * rtw2v0 + he.y * rtw2v1;   // h_e @ r_trans_w2
    #pragma unroll
    for (int m = 1; m < 64; m <<= 1) {
      p_rw1 += __shfl_xor(p_rw1, m);
      p_rw2 += __shfl_xor(p_rw2, m);
      p_hw1 += __shfl_xor(p_hw1, m);
      p_hw2 += __shfl_xor(p_hw2, m);
    }

    const float ch0 = fmaf(he.x, p_rw1, fmaf(re.x, p_hw2, hb0));
    const float ch1 = fmaf(he.y, p_rw1, fmaf(re.y, p_hw2, hb1));
    const float cr0 = fmaf(he.x, p_rw2, fmaf(re.x, p_hw1, rb0));
    const float cr1 = fmaf(he.y, p_rw2, fmaf(re.y, p_hw1, rb1));

    acc_l2 += ch0 * ch0 + ch1 * ch1 + cr0 * cr0 + cr1 * cr1
            + pe.x * pe.x + pe.y * pe.y + ne.x * ne.x + ne.y * ne.y;

    crossbuf[wave][c0] = ch0;
    crossbuf[wave][c0 + 1] = ch1;
    crossbuf[wave][128 + c0] = cr0;
    crossbuf[wave][128 + c0 + 1] = cr1;
    __syncthreads();   // uniform across all waves (same trip counts)

    // pred_t[c0], pred_t[c0+1] = matvec over 256 cross elements
    float pred0 = 0.f, pred1 = 0.f;
    #pragma unroll 4
    for (int i4 = 0; i4 < 32; ++i4) {
      const float4 chv = *reinterpret_cast<const float4*>(&crossbuf[wave][i4 * 4]);
      const float4 crv = *reinterpret_cast<const float4*>(&crossbuf[wave][128 + i4 * 4]);
      #pragma unroll
      for (int k = 0; k < 4; ++k) {
        const int i = i4 * 4 + k;
        const unsigned wt = wp[i * 64 + lane];
        const unsigned wb = wp[(i + 128) * 64 + lane];
        const float wt0 = __uint_as_float(wt << 16);
        const float wt1 = __uint_as_float(wt & 0xffff0000u);
        const float wb0 = __uint_as_float(wb << 16);
        const float wb1 = __uint_as_float(wb & 0xffff0000u);
        const float cc = (&chv.x)[k];
        const float dd = (&crv.x)[k];
        pred0 = fmaf(cc, wt0, fmaf(dd, wb0, pred0));
        pred1 = fmaf(cc, wt1, fmaf(dd, wb1, pred1));
      }
    }
    __syncthreads();   // protect crossbuf before next row's overwrite

    float sp = pred0 * pe.x + pred1 * pe.y;
    float sn = pred0 * ne.x + pred1 * ne.y;
    #pragma unroll
    for (int m = 1; m < 64; m <<= 1) {
      sp += __shfl_xor(sp, m);
      sn += __shfl_xor(sn, m);
    }
    if (lane == 0) {
      const float x = sn - sp;  // -(pos - neg)
      acc_kg += fmaxf(x, 0.f) + log1pf(expf(-fabsf(x)));
    }
  }

  // block reduction
  #pragma unroll
  for (int m = 1; m < 64; m <<= 1) {
    acc_kg += __shfl_xor(acc_kg, m);
    acc_l2 += __shfl_xor(acc_l2, m);
  }
  if (lane == 0) { redbuf[0][wave] = acc_kg; redbuf[1][wave] = acc_l2; }
  __syncthreads();
  if (tid == 0) {
    float kg = 0.f, l2 = 0.f;
    #pragma unroll
    for (int w = 0; w < 8; ++w) { kg += redbuf[0][w]; l2 += redbuf[1][w]; }
    partials[2 * blockIdx.x] = kg;
    partials[2 * blockIdx.x + 1] = l2;
  }
}

__global__ void sur_finalize(const float* __restrict__ partials,
                             float* __restrict__ out) {
  const int t = threadIdx.x;
  float kg = 0.f, l2 = 0.f;
  for (int i = t; i < NBLK; i += 256) {
    kg += partials[2 * i];
    l2 += partials[2 * i + 1];
  }
  #pragma unroll
  for (int m = 1; m < 64; m <<= 1) {
    kg += __shfl_xor(kg, m);
    l2 += __shfl_xor(l2, m);
  }
  __shared__ float s[2][4];
  const int w = t >> 6, lane = t & 63;
  if (lane == 0) { s[0][w] = kg; s[1][w] = l2; }
  __syncthreads();
  if (t == 0) {
    const float K = s[0][0] + s[0][1] + s[0][2] + s[0][3];
    const float L = s[1][0] + s[1][1] + s[1][2] + s[1][3];
    out[0] = K / (float)B_TOTAL + KG_LAMBDA * (0.5f * L / (float)B_TOTAL);
  }
}

extern "C" void kernel_launch(void* const* d_in, const int* in_sizes, int n_in,
                              void* d_out, int out_size, void* d_ws, size_t ws_size,
                              hipStream_t stream) {
  const int* h     = (const int*)d_in[0];
  const int* r     = (const int*)d_in[1];
  const int* pos_t = (const int*)d_in[2];
  const int* neg_t = (const int*)d_in[3];
  const float* ent  = (const float*)d_in[4];
  const float* rel  = (const float*)d_in[5];
  const float* htw1 = (const float*)d_in[6];
  const float* htw2 = (const float*)d_in[7];
  const float* hb   = (const float*)d_in[8];
  const float* rtw1 = (const float*)d_in[9];
  const float* rtw2 = (const float*)d_in[10];
  const float* rb   = (const float*)d_in[11];
  const float* W    = (const float*)d_in[12];
  float* partials = (float*)d_ws;
  float* out = (float*)d_out;

  hipLaunchKernelGGL(sur_main, dim3(NBLK), dim3(TPB), 0, stream,
                     h, r, pos_t, neg_t, ent, rel,
                     htw1, htw2, hb, rtw1, rtw2, rb, W, partials);
  hipLaunchKernelGGL(sur_finalize, dim3(1), dim3(256), 0, stream, partials, out);
}

// Round 2
// 118.151 us; speedup vs baseline: 1.2405x; 1.2405x over previous
//
#include <hip/hip_runtime.h>
#include <hip/hip_bf16.h>

#define B_TOTAL 16384
#define EMB 128
#define NBLK 256            // blocks in main kernel; each block = 4 waves = 64 rows
#define TPB 256
#define KG_LAMBDA 1e-5f
#define WT_STRIDE 264       // bf16 elems per row of Wt (256 + 8 pad = 528 B, 16B-aligned)

typedef float f32x4 __attribute__((ext_vector_type(4)));
typedef unsigned u32x4 __attribute__((ext_vector_type(4)));
typedef __bf16 bf16x8 __attribute__((ext_vector_type(8)));

// RNE float->bf16, packed pair (a in low 16, b in high 16)
__device__ __forceinline__ unsigned pack_bf16x2(float a, float b) {
  unsigned ua = __float_as_uint(a);
  unsigned ub = __float_as_uint(b);
  ua = (ua + 0x7fffu + ((ua >> 16) & 1u)) >> 16;
  ub = (ub + 0x7fffu + ((ub >> 16) & 1u)) >> 16;
  return ua | (ub << 16);
}

__global__ __launch_bounds__(TPB, 2) void sur_fused(
    const int* __restrict__ h, const int* __restrict__ r,
    const int* __restrict__ pos_t, const int* __restrict__ neg_t,
    const float* __restrict__ ent, const float* __restrict__ rel,
    const float* __restrict__ htw1, const float* __restrict__ htw2,
    const float* __restrict__ hbias,
    const float* __restrict__ rtw1, const float* __restrict__ rtw2,
    const float* __restrict__ rbias,
    const float* __restrict__ W, float* __restrict__ partials) {
  // W transposed to [col][k] as bf16, row stride 264 (+8 pad kills b128 read conflicts)
  __shared__ __align__(16) unsigned short Wt[128][WT_STRIDE];  // 67.6 KB
  __shared__ float svec[6 * 128];                              // htw1,htw2,hb,rtw1,rtw2,rb
  __shared__ float redbuf[2][4];

  const int tid = threadIdx.x;
  const int lane = tid & 63;
  const int wave = tid >> 6;
  const int ri = lane & 15;   // A-row within group / B-col within N-tile
  const int q = lane >> 4;    // 0..3: k-chunk selector

  // ---- stage W -> LDS (transpose + cvt to bf16). Coalesced dword reads. ----
  for (int idx = tid; idx < 16384; idx += TPB) {
    const int c = idx & 127;          // output col
    const int kp = idx >> 7;          // k-pair 0..127
    const int k = kp * 2;
    const float f0 = W[k * EMB + c];
    const float f1 = W[(k + 1) * EMB + c];
    *reinterpret_cast<unsigned*>(&Wt[c][k]) = pack_bf16x2(f0, f1);
  }
  // ---- stage the 6 small vectors ----
  for (int i = tid; i < 768; i += TPB) {
    const int v = i >> 7, c = i & 127;
    const float* src = v == 0 ? htw1 : v == 1 ? htw2 : v == 2 ? hbias
                     : v == 3 ? rtw1 : v == 4 ? rtw2 : rbias;
    svec[i] = src[c];
  }
  __syncthreads();

  // ---- prep: gather h_e, r_e for this wave's 16 rows ----
  const int rowbase = blockIdx.x * 64 + wave * 16;
  const int hoff = h[rowbase + ri] * EMB;
  const int roff = r[rowbase + ri] * EMB;

  float he[4][8], re[4][8];
  #pragma unroll
  for (int kt = 0; kt < 4; ++kt) {
    const int c0 = kt * 32 + q * 8;
    const float4 a0 = *reinterpret_cast<const float4*>(ent + hoff + c0);
    const float4 a1 = *reinterpret_cast<const float4*>(ent + hoff + c0 + 4);
    const float4 b0 = *reinterpret_cast<const float4*>(rel + roff + c0);
    const float4 b1 = *reinterpret_cast<const float4*>(rel + roff + c0 + 4);
    he[kt][0] = a0.x; he[kt][1] = a0.y; he[kt][2] = a0.z; he[kt][3] = a0.w;
    he[kt][4] = a1.x; he[kt][5] = a1.y; he[kt][6] = a1.z; he[kt][7] = a1.w;
    re[kt][0] = b0.x; re[kt][1] = b0.y; re[kt][2] = b0.z; re[kt][3] = b0.w;
    re[kt][4] = b1.x; re[kt][5] = b1.y; re[kt][6] = b1.z; re[kt][7] = b1.w;
  }

  // ---- four per-row dots (partials over this lane's 32 cols, reduce over q) ----
  float prw1 = 0.f, prw2 = 0.f, phw1 = 0.f, phw2 = 0.f;
  #pragma unroll
  for (int kt = 0; kt < 4; ++kt) {
    const int c0 = kt * 32 + q * 8;
    #pragma unroll
    for (int j = 0; j < 8; ++j) {
      prw1 = fmaf(re[kt][j], svec[0 * 128 + c0 + j], prw1);  // r_e @ h_trans_w1
      prw2 = fmaf(re[kt][j], svec[1 * 128 + c0 + j], prw2);  // r_e @ h_trans_w2
      phw1 = fmaf(he[kt][j], svec[3 * 128 + c0 + j], phw1);  // h_e @ r_trans_w1
      phw2 = fmaf(he[kt][j], svec[4 * 128 + c0 + j], phw2);  // h_e @ r_trans_w2
    }
  }
  prw1 += __shfl_xor(prw1, 16); prw2 += __shfl_xor(prw2, 16);
  phw1 += __shfl_xor(phw1, 16); phw2 += __shfl_xor(phw2, 16);
  prw1 += __shfl_xor(prw1, 32); prw2 += __shfl_xor(prw2, 32);
  phw1 += __shfl_xor(phw1, 32); phw2 += __shfl_xor(phw2, 32);

  // ---- cross terms -> bf16 A-fragments (in-register, frag layout by construction) ----
  float acc_l2 = 0.f;
  u32x4 afu[8];  // afu[0..3] = cross_h K-tiles, afu[4..7] = cross_r K-tiles
  #pragma unroll
  for (int kt = 0; kt < 4; ++kt) {
    const int c0 = kt * 32 + q * 8;
    float ch[8], cr[8];
    #pragma unroll
    for (int j = 0; j < 8; ++j) {
      const float hb = svec[2 * 128 + c0 + j];
      const float rb = svec[5 * 128 + c0 + j];
      ch[j] = fmaf(he[kt][j], prw1, fmaf(re[kt][j], phw2, hb));
      cr[j] = fmaf(he[kt][j], prw2, fmaf(re[kt][j], phw1, rb));
      acc_l2 += ch[j] * ch[j] + cr[j] * cr[j];
    }
    #pragma unroll
    for (int d = 0; d < 4; ++d) {
      afu[kt][d]     = pack_bf16x2(ch[2 * d], ch[2 * d + 1]);
      afu[kt + 4][d] = pack_bf16x2(cr[2 * d], cr[2 * d + 1]);
    }
  }

  // ---- issue pos/neg gathers early (latency hides under MFMA) ----
  int pidx[4], nidx[4];
  #pragma unroll
  for (int g = 0; g < 4; ++g) {
    pidx[g] = pos_t[rowbase + q * 4 + g] * EMB;
    nidx[g] = neg_t[rowbase + q * 4 + g] * EMB;
  }
  float pe[4][8], ne[4][8];
  #pragma unroll
  for (int g = 0; g < 4; ++g) {
    #pragma unroll
    for (int n = 0; n < 8; ++n) {
      pe[g][n] = ent[pidx[g] + n * 16 + ri];  // pred C-layout col = 16n + ri
      ne[g][n] = ent[nidx[g] + n * 16 + ri];
    }
  }

  // ---- GEMM: pred[16][128] = cross[16][256] @ W[256][128] via 64 MFMAs ----
  f32x4 acc[8];
  #pragma unroll
  for (int n = 0; n < 8; ++n) acc[n] = 0.f;
  #pragma unroll
  for (int t = 0; t < 8; ++t) {
    const bf16x8 av = __builtin_bit_cast(bf16x8, afu[t]);
    #pragma unroll
    for (int n = 0; n < 8; ++n) {
      const bf16x8 bv = *reinterpret_cast<const bf16x8*>(&Wt[n * 16 + ri][t * 32 + q * 8]);
      acc[n] = __builtin_amdgcn_mfma_f32_16x16x32_bf16(av, bv, acc[n], 0, 0, 0);
    }
  }

  // ---- scores: pred[row=q*4+g][col=16n+ri] vs pe/ne; reduce over ri bits ----
  float sp[4] = {0.f, 0.f, 0.f, 0.f}, sn[4] = {0.f, 0.f, 0.f, 0.f};
  #pragma unroll
  for (int n = 0; n < 8; ++n) {
    #pragma unroll
    for (int g = 0; g < 4; ++g) {
      sp[g] = fmaf(acc[n][g], pe[g][n], sp[g]);
      sn[g] = fmaf(acc[n][g], ne[g][n], sn[g]);
      acc_l2 += pe[g][n] * pe[g][n] + ne[g][n] * ne[g][n];
    }
  }
  #pragma unroll
  for (int m = 1; m < 16; m <<= 1) {
    #pragma unroll
    for (int g = 0; g < 4; ++g) {
      sp[g] += __shfl_xor(sp[g], m);
      sn[g] += __shfl_xor(sn[g], m);
    }
  }
  float acc_kg = 0.f;
  if (ri == 0) {
    #pragma unroll
    for (int g = 0; g < 4; ++g) {
      const float x = sn[g] - sp[g];  // == -(pos - neg)
      acc_kg += fmaxf(x, 0.f) + log1pf(expf(-fabsf(x)));
    }
  }

  // ---- reductions ----
  float kg = acc_kg, l2 = acc_l2;
  #pragma unroll
  for (int m = 1; m < 64; m <<= 1) {
    kg += __shfl_xor(kg, m);
    l2 += __shfl_xor(l2, m);
  }
  if (lane == 0) { redbuf[0][wave] = kg; redbuf[1][wave] = l2; }
  __syncthreads();
  if (tid == 0) {
    float K = 0.f, L = 0.f;
    #pragma unroll
    for (int w = 0; w < 4; ++w) { K += redbuf[0][w]; L += redbuf[1][w]; }
    partials[2 * blockIdx.x] = K;
    partials[2 * blockIdx.x + 1] = L;
  }
}

__global__ void sur_finalize(const float* __restrict__ partials,
                             float* __restrict__ out) {
  const int t = threadIdx.x;
  float kg = 0.f, l2 = 0.f;
  for (int i = t; i < NBLK; i += 256) {
    kg += partials[2 * i];
    l2 += partials[2 * i + 1];
  }
  #pragma unroll
  for (int m = 1; m < 64; m <<= 1) {
    kg += __shfl_xor(kg, m);
    l2 += __shfl_xor(l2, m);
  }
  __shared__ float s[2][4];
  const int w = t >> 6, lane = t & 63;
  if (lane == 0) { s[0][w] = kg; s[1][w] = l2; }
  __syncthreads();
  if (t == 0) {
    const float K = s[0][0] + s[0][1] + s[0][2] + s[0][3];
    const float L = s[1][0] + s[1][1] + s[1][2] + s[1][3];
    out[0] = K / (float)B_TOTAL + KG_LAMBDA * (0.5f * L / (float)B_TOTAL);
  }
}

extern "C" void kernel_launch(void* const* d_in, const int* in_sizes, int n_in,
                              void* d_out, int out_size, void* d_ws, size_t ws_size,
                              hipStream_t stream) {
  const int* h     = (const int*)d_in[0];
  const int* r     = (const int*)d_in[1];
  const int* pos_t = (const int*)d_in[2];
  const int* neg_t = (const int*)d_in[3];
  const float* ent  = (const float*)d_in[4];
  const float* rel  = (const float*)d_in[5];
  const float* htw1 = (const float*)d_in[6];
  const float* htw2 = (const float*)d_in[7];
  const float* hb   = (const float*)d_in[8];
  const float* rtw1 = (const float*)d_in[9];
  const float* rtw2 = (const float*)d_in[10];
  const float* rb   = (const float*)d_in[11];
  const float* W    = (const float*)d_in[12];
  float* partials = (float*)d_ws;
  float* out = (float*)d_out;

  hipLaunchKernelGGL(sur_fused, dim3(NBLK), dim3(TPB), 0, stream,
                     h, r, pos_t, neg_t, ent, rel,
                     htw1, htw2, hb, rtw1, rtw2, rb, W, partials);
  hipLaunchKernelGGL(sur_finalize, dim3(1), dim3(256), 0, stream, partials, out);
}

// Round 5
// 116.073 us; speedup vs baseline: 1.2627x; 1.0179x over previous
//
#include <hip/hip_runtime.h>
#include <hip/hip_bf16.h>

#define B_TOTAL 16384
#define EMB 128
#define NBLK 256            // main kernel blocks; each = 4 waves = 64 rows
#define TPB 256
#define KG_LAMBDA 1e-5f
#define WT_STRIDE 264       // bf16 elems per Wt row (256 + 8 pad = 528 B)
#define IMG_BYTES 73728     // 128*264*2 (Wt) + 768*4 (svec) + pad -> 18*4096
#define IMG_DW (IMG_BYTES / 4)
#define WT_DW 16896         // 128 rows * 132 dwords
#define SVEC_BYTE_OFF 67584 // WT_DW*4

typedef float f32x4 __attribute__((ext_vector_type(4)));
typedef unsigned u32x4 __attribute__((ext_vector_type(4)));
typedef __bf16 bf16x8 __attribute__((ext_vector_type(8)));

// RNE float->bf16, packed pair (a in low 16, b in high 16)
__device__ __forceinline__ unsigned pack_bf16x2(float a, float b) {
  unsigned ua = __float_as_uint(a);
  unsigned ub = __float_as_uint(b);
  ua = (ua + 0x7fffu + ((ua >> 16) & 1u)) >> 16;
  ub = (ub + 0x7fffu + ((ub >> 16) & 1u)) >> 16;
  return ua | (ub << 16);
}

// Build the LDS image in d_ws: Wt[c][kp] bf16-pairs (c*132+kp dwords), then svec.
__global__ __launch_bounds__(256) void sur_prep(
    const float* __restrict__ W,
    const float* __restrict__ htw1, const float* __restrict__ htw2,
    const float* __restrict__ hbias,
    const float* __restrict__ rtw1, const float* __restrict__ rtw2,
    const float* __restrict__ rbias,
    unsigned* __restrict__ img) {
  const int idx = blockIdx.x * 256 + threadIdx.x;  // [0, IMG_DW)
  if (idx < WT_DW) {
    const int c = idx / 132;          // Wt row (output col)
    const int kp = idx - c * 132;     // k-pair (128 real + 4 pad)
    unsigned v = 0;
    if (kp < 128) {
      const float f0 = W[(2 * kp) * EMB + c];
      const float f1 = W[(2 * kp + 1) * EMB + c];
      v = pack_bf16x2(f0, f1);
    }
    img[idx] = v;                     // coalesced writes
  } else {
    const int j = idx - WT_DW;
    float val = 0.f;
    if (j < 768) {
      const int vsel = j >> 7, cc = j & 127;
      const float* src = vsel == 0 ? htw1 : vsel == 1 ? htw2 : vsel == 2 ? hbias
                       : vsel == 3 ? rtw1 : vsel == 4 ? rtw2 : rbias;
      val = src[cc];
    }
    img[idx] = __float_as_uint(val);
  }
}

__global__ __launch_bounds__(TPB, 2) void sur_fused(
    const int* __restrict__ h, const int* __restrict__ r,
    const int* __restrict__ pos_t, const int* __restrict__ neg_t,
    const float* __restrict__ ent, const float* __restrict__ rel,
    const unsigned* __restrict__ img, float* __restrict__ out) {
  __shared__ __align__(16) unsigned char smem[IMG_BYTES];
  __shared__ float redbuf[2][4];
  unsigned short (*Wt)[WT_STRIDE] = (unsigned short(*)[WT_STRIDE])smem;
  const float* svec = (const float*)(smem + SVEC_BYTE_OFF);

  const int tid = threadIdx.x;
  const int lane = tid & 63;
  const int wave = tid >> 6;
  const int ri = lane & 15;   // A-row in group / B-col in N-tile
  const int q = lane >> 4;    // 0..3: k-chunk selector

  // ---- issue index loads first (longest dependency chains) ----
  const int rowbase = blockIdx.x * 64 + wave * 16;
  const int hidx = h[rowbase + ri] * EMB;
  const int ridx = r[rowbase + ri] * EMB;
  int pidx[4], nidx[4];
  #pragma unroll
  for (int g = 0; g < 4; ++g) {
    pidx[g] = pos_t[rowbase + q * 4 + g] * EMB;
    nidx[g] = neg_t[rowbase + q * 4 + g] * EMB;
  }

  // ---- stage prebuilt image -> LDS: 18 coalesced b128 copies/thread ----
  {
    const float4* gsrc = (const float4*)img;
    float4* ldst = (float4*)smem;
    #pragma unroll
    for (int i = 0; i < IMG_BYTES / 16 / TPB; ++i)
      ldst[i * TPB + tid] = gsrc[i * TPB + tid];
  }

  // ---- gather h_e, r_e rows (vectorized) ----
  float he[4][8], re[4][8];
  #pragma unroll
  for (int kt = 0; kt < 4; ++kt) {
    const int c0 = kt * 32 + q * 8;
    const float4 a0 = *reinterpret_cast<const float4*>(ent + hidx + c0);
    const float4 a1 = *reinterpret_cast<const float4*>(ent + hidx + c0 + 4);
    const float4 b0 = *reinterpret_cast<const float4*>(rel + ridx + c0);
    const float4 b1 = *reinterpret_cast<const float4*>(rel + ridx + c0 + 4);
    he[kt][0] = a0.x; he[kt][1] = a0.y; he[kt][2] = a0.z; he[kt][3] = a0.w;
    he[kt][4] = a1.x; he[kt][5] = a1.y; he[kt][6] = a1.z; he[kt][7] = a1.w;
    re[kt][0] = b0.x; re[kt][1] = b0.y; re[kt][2] = b0.z; re[kt][3] = b0.w;
    re[kt][4] = b1.x; re[kt][5] = b1.y; re[kt][6] = b1.z; re[kt][7] = b1.w;
  }

  // ---- gather pos/neg rows in pred C-layout (col = 16n + ri; 64B segments) ----
  float pe[4][8], ne[4][8];
  #pragma unroll
  for (int g = 0; g < 4; ++g) {
    #pragma unroll
    for (int n = 0; n < 8; ++n) {
      pe[g][n] = ent[pidx[g] + n * 16 + ri];
      ne[g][n] = ent[nidx[g] + n * 16 + ri];
    }
  }

  __syncthreads();  // image staged; gathers drained under the same wait

  // ---- four per-row dots (partials over this lane's 32 cols, reduce over q) ----
  float prw1 = 0.f, prw2 = 0.f, phw1 = 0.f, phw2 = 0.f;
  #pragma unroll
  for (int kt = 0; kt < 4; ++kt) {
    const int c0 = kt * 32 + q * 8;
    #pragma unroll
    for (int j = 0; j < 8; ++j) {
      prw1 = fmaf(re[kt][j], svec[0 * 128 + c0 + j], prw1);  // r_e @ h_trans_w1
      prw2 = fmaf(re[kt][j], svec[1 * 128 + c0 + j], prw2);  // r_e @ h_trans_w2
      phw1 = fmaf(he[kt][j], svec[3 * 128 + c0 + j], phw1);  // h_e @ r_trans_w1
      phw2 = fmaf(he[kt][j], svec[4 * 128 + c0 + j], phw2);  // h_e @ r_trans_w2
    }
  }
  prw1 += __shfl_xor(prw1, 16); prw2 += __shfl_xor(prw2, 16);
  phw1 += __shfl_xor(phw1, 16); phw2 += __shfl_xor(phw2, 16);
  prw1 += __shfl_xor(prw1, 32); prw2 += __shfl_xor(prw2, 32);
  phw1 += __shfl_xor(phw1, 32); phw2 += __shfl_xor(phw2, 32);

  // ---- cross terms -> bf16 A-fragments (frag layout by construction) ----
  float acc_l2 = 0.f;
  u32x4 afu[8];  // [0..3] cross_h K-tiles, [4..7] cross_r K-tiles
  #pragma unroll
  for (int kt = 0; kt < 4; ++kt) {
    const int c0 = kt * 32 + q * 8;
    float ch[8], cr[8];
    #pragma unroll
    for (int j = 0; j < 8; ++j) {
      const float hb = svec[2 * 128 + c0 + j];
      const float rb = svec[5 * 128 + c0 + j];
      ch[j] = fmaf(he[kt][j], prw1, fmaf(re[kt][j], phw2, hb));
      cr[j] = fmaf(he[kt][j], prw2, fmaf(re[kt][j], phw1, rb));
      acc_l2 += ch[j] * ch[j] + cr[j] * cr[j];
    }
    #pragma unroll
    for (int d = 0; d < 4; ++d) {
      afu[kt][d]     = pack_bf16x2(ch[2 * d], ch[2 * d + 1]);
      afu[kt + 4][d] = pack_bf16x2(cr[2 * d], cr[2 * d + 1]);
    }
  }

  // ---- GEMM: pred[16][128] = cross[16][256] @ W[256][128], 64 MFMAs ----
  f32x4 acc[8];
  #pragma unroll
  for (int n = 0; n < 8; ++n) acc[n] = 0.f;
  #pragma unroll
  for (int t = 0; t < 8; ++t) {
    const bf16x8 av = __builtin_bit_cast(bf16x8, afu[t]);
    #pragma unroll
    for (int n = 0; n < 8; ++n) {
      const bf16x8 bv = *reinterpret_cast<const bf16x8*>(&Wt[n * 16 + ri][t * 32 + q * 8]);
      acc[n] = __builtin_amdgcn_mfma_f32_16x16x32_bf16(av, bv, acc[n], 0, 0, 0);
    }
  }

  // ---- scores: pred[row=q*4+g][col=16n+ri] vs pe/ne; reduce over ri bits ----
  float sp[4] = {0.f, 0.f, 0.f, 0.f}, sn[4] = {0.f, 0.f, 0.f, 0.f};
  #pragma unroll
  for (int n = 0; n < 8; ++n) {
    #pragma unroll
    for (int g = 0; g < 4; ++g) {
      sp[g] = fmaf(acc[n][g], pe[g][n], sp[g]);
      sn[g] = fmaf(acc[n][g], ne[g][n], sn[g]);
      acc_l2 += pe[g][n] * pe[g][n] + ne[g][n] * ne[g][n];
    }
  }
  #pragma unroll
  for (int m = 1; m < 16; m <<= 1) {
    #pragma unroll
    for (int g = 0; g < 4; ++g) {
      sp[g] += __shfl_xor(sp[g], m);
      sn[g] += __shfl_xor(sn[g], m);
    }
  }
  float acc_kg = 0.f;
  if (ri == 0) {
    #pragma unroll
    for (int g = 0; g < 4; ++g) {
      const float x = sn[g] - sp[g];  // == -(pos - neg)
      acc_kg += fmaxf(x, 0.f) + log1pf(expf(-fabsf(x)));
    }
  }

  // ---- block reduction + single atomic ----
  float kg = acc_kg, l2 = acc_l2;
  #pragma unroll
  for (int m = 1; m < 64; m <<= 1) {
    kg += __shfl_xor(kg, m);
    l2 += __shfl_xor(l2, m);
  }
  if (lane == 0) { redbuf[0][wave] = kg; redbuf[1][wave] = l2; }
  __syncthreads();
  if (tid == 0) {
    const float K = redbuf[0][0] + redbuf[0][1] + redbuf[0][2] + redbuf[0][3];
    const float L = redbuf[1][0] + redbuf[1][1] + redbuf[1][2] + redbuf[1][3];
    atomicAdd(out, (K + KG_LAMBDA * 0.5f * L) * (1.0f / (float)B_TOTAL));
  }
}

extern "C" void kernel_launch(void* const* d_in, const int* in_sizes, int n_in,
                              void* d_out, int out_size, void* d_ws, size_t ws_size,
                              hipStream_t stream) {
  const int* h     = (const int*)d_in[0];
  const int* r     = (const int*)d_in[1];
  const int* pos_t = (const int*)d_in[2];
  const int* neg_t = (const int*)d_in[3];
  const float* ent  = (const float*)d_in[4];
  const float* rel  = (const float*)d_in[5];
  const float* htw1 = (const float*)d_in[6];
  const float* htw2 = (const float*)d_in[7];
  const float* hb   = (const float*)d_in[8];
  const float* rtw1 = (const float*)d_in[9];
  const float* rtw2 = (const float*)d_in[10];
  const float* rb   = (const float*)d_in[11];
  const float* W    = (const float*)d_in[12];
  unsigned* img = (unsigned*)d_ws;
  float* out = (float*)d_out;

  hipMemsetAsync(d_out, 0, sizeof(float), stream);
  hipLaunchKernelGGL(sur_prep, dim3(IMG_DW / 256), dim3(256), 0, stream,
                     W, htw1, htw2, hb, rtw1, rtw2, rb, img);
  hipLaunchKernelGGL(sur_fused, dim3(NBLK), dim3(TPB), 0, stream,
                     h, r, pos_t, neg_t, ent, rel, img, out);
}